// Round 2
// baseline (549.106 us; speedup 1.0000x reference)
//
#include <hip/hip_runtime.h>

// LoRA forward: out = 0.25 * (x @ (A*sA)^T) @ (B*sB)^T
// x: [16384, 4096] f32, A: [64, 4096] f32, B: [4096, 64] f32
//
// v2 (resubmit; round-1 failure was container infra, not the kernel):
// fused, barrier-free streaming design.
//  - rank=64 => A-panel (512 KB bf16) and B-panel (512 KB bf16) are L2-resident;
//    MFMA fragments are loaded DIRECTLY from global (16 B/lane, coalesced),
//    so the K-loop has ZERO barriers and ZERO LDS traffic. The old version's
//    128 barrier-coupled staging iterations were the bottleneck (~1.7 TB/s).
//  - block = 16 rows (one 16x16x32 m-tile), 4 waves split K (1024 each),
//    partials reduced once through LDS (2 barriers per block TOTAL).
//  - phase B: operand-swapped MFMA (A-op = B-rows, B-op = h-rows) so each
//    lane owns 4 consecutive n -> float4 stores; h lives only in LDS.

#define M_TOTAL 16384
#define DIN     4096
#define DOUT    4096
#define RANK    64

typedef __bf16 bf16_8 __attribute__((ext_vector_type(8)));
typedef __bf16 bf16_4 __attribute__((ext_vector_type(4)));
typedef float  f32x4  __attribute__((ext_vector_type(4)));

// ---------------- prep: dequantize A and B into bf16 ----------------
__global__ __launch_bounds__(256) void prep_kernel(
    const float* __restrict__ A, const float* __restrict__ Bm,
    const float* __restrict__ sA, const float* __restrict__ sB,
    __bf16* __restrict__ Abf, __bf16* __restrict__ Bbf) {
  int i = (blockIdx.x * 256 + threadIdx.x) * 4;
  float4 a = *(const float4*)(A + i);
  float sa = sA[i >> 12];                 // A row = i / 4096
  bf16_4 va;
  va[0] = (__bf16)(a.x * sa); va[1] = (__bf16)(a.y * sa);
  va[2] = (__bf16)(a.z * sa); va[3] = (__bf16)(a.w * sa);
  *(bf16_4*)(Abf + i) = va;

  float4 b = *(const float4*)(Bm + i);
  float sb = sB[i >> 6] * 0.25f;          // B row = i / 64; fold SCALING
  bf16_4 vb;
  vb[0] = (__bf16)(b.x * sb); vb[1] = (__bf16)(b.y * sb);
  vb[2] = (__bf16)(b.z * sb); vb[3] = (__bf16)(b.w * sb);
  *(bf16_4*)(Bbf + i) = vb;
}

// ---------------- fused LoRA kernel ----------------
// grid = 1024 blocks (16 rows each), 256 threads = 4 waves.
// Phase A: wave w accumulates h-partial over k in [w*1024, w*1024+1024).
//   x fragment loaded directly: lane(lr,quad) reads x[mBase+lr][k+quad*8 .. +7]
//   A fragment loaded directly from L2-hot Abf, 4 n-tiles (ranks 0..63).
// Reduce: 4 partials summed in f32 via LDS, h tile (16x64 bf16) -> LDS.
// Phase B: wave w owns n in [w*1024, w*1024+1024); 64 n-tiles, streaming.
__global__ __launch_bounds__(256, 4) void lora_kernel(
    const float* __restrict__ x, const __bf16* __restrict__ Abf,
    const __bf16* __restrict__ Bbf, float* __restrict__ out) {
  __shared__ alignas(16) float  part[4 * 1024];  // 4 wave-partials, 16x64 f32 each
  __shared__ alignas(16) __bf16 hs[16 * RANK];   // reduced h tile, bf16

  const int t    = threadIdx.x;
  const int lane = t & 63;
  const int w    = t >> 6;        // wave id: K-split (A) / n-quarter (B)
  const int lr   = lane & 15;
  const int quad = lane >> 4;
  const int mBase = blockIdx.x * 16;

  // ---- phase A: h-partial = x[16 rows][k-quarter] @ A^T ----
  const float*  xg = x   + (size_t)(mBase + lr) * DIN + w * 1024 + quad * 8;
  const __bf16* ag = Abf + (size_t)lr * DIN           + w * 1024 + quad * 8;

  f32x4 acc0 = {0.f,0.f,0.f,0.f};
  f32x4 acc1 = {0.f,0.f,0.f,0.f};
  f32x4 acc2 = {0.f,0.f,0.f,0.f};
  f32x4 acc3 = {0.f,0.f,0.f,0.f};

  // 1-deep register prefetch; no barriers -> waves pipeline independently.
  float4 f0 = *(const float4*)(xg);
  float4 f1 = *(const float4*)(xg + 4);
  bf16_8 a0 = *(const bf16_8*)(ag);
  bf16_8 a1 = *(const bf16_8*)(ag + 16 * DIN);
  bf16_8 a2 = *(const bf16_8*)(ag + 32 * DIN);
  bf16_8 a3 = *(const bf16_8*)(ag + 48 * DIN);

  for (int k = 32; k <= 1024; k += 32) {
    float4 g0 = f0, g1 = f1;
    bf16_8 c0 = a0, c1 = a1, c2 = a2, c3 = a3;
    if (k < 1024) {               // uniform branch; guards OOB on last iter
      f0 = *(const float4*)(xg + k);
      f1 = *(const float4*)(xg + k + 4);
      a0 = *(const bf16_8*)(ag + k);
      a1 = *(const bf16_8*)(ag + k + 16 * DIN);
      a2 = *(const bf16_8*)(ag + k + 32 * DIN);
      a3 = *(const bf16_8*)(ag + k + 48 * DIN);
    }
    bf16_8 xv;
    xv[0] = (__bf16)g0.x; xv[1] = (__bf16)g0.y;
    xv[2] = (__bf16)g0.z; xv[3] = (__bf16)g0.w;
    xv[4] = (__bf16)g1.x; xv[5] = (__bf16)g1.y;
    xv[6] = (__bf16)g1.z; xv[7] = (__bf16)g1.w;
    acc0 = __builtin_amdgcn_mfma_f32_16x16x32_bf16(xv, c0, acc0, 0, 0, 0);
    acc1 = __builtin_amdgcn_mfma_f32_16x16x32_bf16(xv, c1, acc1, 0, 0, 0);
    acc2 = __builtin_amdgcn_mfma_f32_16x16x32_bf16(xv, c2, acc2, 0, 0, 0);
    acc3 = __builtin_amdgcn_mfma_f32_16x16x32_bf16(xv, c3, acc3, 0, 0, 0);
  }

  // write partials: part[w][row = quad*4+i][rank = nt*16+lr]
  {
    float* pw = part + w * 1024;
#pragma unroll
    for (int i = 0; i < 4; ++i) {
      pw[(quad * 4 + i) * 64 +      lr] = acc0[i];
      pw[(quad * 4 + i) * 64 + 16 + lr] = acc1[i];
      pw[(quad * 4 + i) * 64 + 32 + lr] = acc2[i];
      pw[(quad * 4 + i) * 64 + 48 + lr] = acc3[i];
    }
  }
  __syncthreads();

  // reduce 4 partials -> hs (bf16). thread t owns elements 4t..4t+3.
  {
    const f32x4* pp = (const f32x4*)part;
    f32x4 s = pp[t] + pp[t + 256] + pp[t + 512] + pp[t + 768];
    bf16_4 hv;
    hv[0] = (__bf16)s[0]; hv[1] = (__bf16)s[1];
    hv[2] = (__bf16)s[2]; hv[3] = (__bf16)s[3];
    ((bf16_4*)hs)[t] = hv;
  }
  __syncthreads();

  // ---- phase B: out[16 rows][n-quarter] = h @ B^T ----
  // h fragment (B-operand): lane holds h[mBase+lr][k = quad*8 .. +7], two k-windows.
  bf16_8 hf0 = *(const bf16_8*)&hs[lr * RANK + quad * 8];
  bf16_8 hf1 = *(const bf16_8*)&hs[lr * RANK + 32 + quad * 8];

  const __bf16* bg = Bbf + (size_t)(w * 1024 + lr) * RANK + quad * 8;
  float* og = out + (size_t)(mBase + lr) * DOUT + w * 1024;

  // operand-swapped MFMA: D[row = n(quad*4+i)][col = m(lr)]
  // -> lane stores out[mBase+lr][nBase + nt*16 + quad*4 .. +3] as float4.
#pragma unroll 4
  for (int nt = 0; nt < 64; ++nt) {
    bf16_8 b0 = *(const bf16_8*)(bg + nt * 16 * RANK);
    bf16_8 b1 = *(const bf16_8*)(bg + nt * 16 * RANK + 32);
    f32x4 o = {0.f, 0.f, 0.f, 0.f};
    o = __builtin_amdgcn_mfma_f32_16x16x32_bf16(b0, hf0, o, 0, 0, 0);
    o = __builtin_amdgcn_mfma_f32_16x16x32_bf16(b1, hf1, o, 0, 0, 0);
    *(f32x4*)(og + nt * 16 + quad * 4) = o;
  }
}

extern "C" void kernel_launch(void* const* d_in, const int* in_sizes, int n_in,
                              void* d_out, int out_size, void* d_ws, size_t ws_size,
                              hipStream_t stream) {
  const float* x  = (const float*)d_in[0];
  const float* A  = (const float*)d_in[1];
  const float* Bm = (const float*)d_in[2];
  const float* sA = (const float*)d_in[3];
  const float* sB = (const float*)d_in[4];
  float* out = (float*)d_out;

  // workspace: Abf (512 KB) | Bbf (512 KB). h stays in LDS now.
  __bf16* Abf = (__bf16*)d_ws;
  __bf16* Bbf = Abf + (size_t)RANK * DIN;

  prep_kernel<<<256, 256, 0, stream>>>(A, Bm, sA, sB, Abf, Bbf);
  lora_kernel<<<M_TOTAL / 16, 256, 0, stream>>>(x, Abf, Bbf, out);
}

// Round 3
// 501.529 us; speedup vs baseline: 1.0949x; 1.0949x over previous
//
#include <hip/hip_runtime.h>

// LoRA forward: out = 0.25 * (x @ (A*sA)^T) @ (B*sB)^T
// x: [16384, 4096] f32, A: [64, 4096] f32, B: [4096, 64] f32
//
// v3: DRAM-granularity-optimized two-kernel design.
// Diagnosis from v2 counters: 1.7 TB/s with VALU/MFMA ~3% and ample in-flight
// bytes => HBM row-buffer thrash from 16-row-scattered 64-256B accesses.
// Fix: every global access is a 1KB+ contiguous run.
//  K1: x staged f32 via global_load_lds, one full 1KB row-chunk per wave-issue,
//      double-buffered; bf16 convert at ds_read; A-frags from L2-hot panel.
//  K2: out tile computed into LDS, then copied out linearly (1KB/instruction).

#define M_TOTAL 16384
#define DIN     4096
#define DOUT    4096
#define RANK    64

typedef __bf16 bf16_8 __attribute__((ext_vector_type(8)));
typedef __bf16 bf16_4 __attribute__((ext_vector_type(4)));
typedef float  f32x4  __attribute__((ext_vector_type(4)));

#define GLDS16(g, l) __builtin_amdgcn_global_load_lds( \
    (const __attribute__((address_space(1))) void*)(g), \
    (__attribute__((address_space(3))) void*)(l), 16, 0, 0)

// ---------------- prep: dequantize A and B into bf16 ----------------
__global__ __launch_bounds__(256) void prep_kernel(
    const float* __restrict__ A, const float* __restrict__ Bm,
    const float* __restrict__ sA, const float* __restrict__ sB,
    __bf16* __restrict__ Abf, __bf16* __restrict__ Bbf) {
  int i = (blockIdx.x * 256 + threadIdx.x) * 4;
  float4 a = *(const float4*)(A + i);
  float sa = sA[i >> 12];                 // A row = i / 4096
  bf16_4 va;
  va[0] = (__bf16)(a.x * sa); va[1] = (__bf16)(a.y * sa);
  va[2] = (__bf16)(a.z * sa); va[3] = (__bf16)(a.w * sa);
  *(bf16_4*)(Abf + i) = va;

  float4 b = *(const float4*)(Bm + i);
  float sb = sB[i >> 6] * 0.25f;          // B row = i / 64; fold SCALING
  bf16_4 vb;
  vb[0] = (__bf16)(b.x * sb); vb[1] = (__bf16)(b.y * sb);
  vb[2] = (__bf16)(b.z * sb); vb[3] = (__bf16)(b.w * sb);
  *(bf16_4*)(Bbf + i) = vb;
}

// ---------------- K1: h[M,64] = x[M,4096] @ Abf[64,4096]^T ----------------
// 512 blocks x 256 thr (4 waves: mt = w&1 m-tile, kh = w>>1 k-half).
// BK=256 f32 staged to LDS, double-buffered. Stage: wave w issue j covers LDS
// row r = w + j*4 as ONE contiguous 1KB global read (lane^(r&1) 16B-swizzled
// source so swizzled ds_reads are bank-uniform; rule: linear LDS dest +
// inverse-swizzled source + swizzled read).
__global__ __launch_bounds__(256, 2) void gemm1_kernel(
    const float* __restrict__ x, const __bf16* __restrict__ Abf,
    __bf16* __restrict__ h) {
  __shared__ alignas(16) float xs[2][32][256];   // 2 x 32KB
  __shared__ alignas(16) float part[4][16][64];  // 16KB cross-wave reduce

  const int t    = threadIdx.x;
  const int lane = t & 63;
  const int w    = t >> 6;
  const int lr   = lane & 15;
  const int quad = lane >> 4;
  const int mt   = w & 1;
  const int kh   = w >> 1;
  const int mBase = blockIdx.x * 32;

  // staging source: rows r = w + j*4 all share r&1 == w&1
  const int swz = w & 1;
  const float* xsrc = x + (size_t)(mBase + w) * DIN + ((lane ^ swz) << 2);

  const int row = mt * 16 + lr;   // LDS row this lane reads fragments from
  const int rs  = row & 1;        // read-side 16B swizzle bit

  f32x4 acc0 = {0.f,0.f,0.f,0.f};
  f32x4 acc1 = {0.f,0.f,0.f,0.f};
  f32x4 acc2 = {0.f,0.f,0.f,0.f};
  f32x4 acc3 = {0.f,0.f,0.f,0.f};

  // prologue: stage step 0 into buf 0
#pragma unroll
  for (int j = 0; j < 8; ++j)
    GLDS16(xsrc + (size_t)j * 4 * DIN, &xs[0][w + j * 4][0]);
  __syncthreads();

  for (int s = 0; s < 16; ++s) {
    const int buf = s & 1;
    if (s + 1 < 16) {                       // stage next tile into buf^1
      const float* src = xsrc + (s + 1) * 256;
#pragma unroll
      for (int j = 0; j < 8; ++j)
        GLDS16(src + (size_t)j * 4 * DIN, &xs[buf ^ 1][w + j * 4][0]);
    }
    const int k0 = s * 256;
#pragma unroll
    for (int ks = 0; ks < 4; ++ks) {
      const float* px = &xs[buf][row][kh * 128 + ks * 32 + quad * 8];
      f32x4 lo = *(const f32x4*)(px + (rs ? 4 : 0));
      f32x4 hi = *(const f32x4*)(px + (rs ? 0 : 4));
      bf16_8 xv;
      xv[0]=(__bf16)lo[0]; xv[1]=(__bf16)lo[1]; xv[2]=(__bf16)lo[2]; xv[3]=(__bf16)lo[3];
      xv[4]=(__bf16)hi[0]; xv[5]=(__bf16)hi[1]; xv[6]=(__bf16)hi[2]; xv[7]=(__bf16)hi[3];

      const __bf16* ap = Abf + (size_t)lr * DIN + k0 + kh * 128 + ks * 32 + quad * 8;
      bf16_8 a0 = *(const bf16_8*)(ap);
      bf16_8 a1 = *(const bf16_8*)(ap + 16 * DIN);
      bf16_8 a2 = *(const bf16_8*)(ap + 32 * DIN);
      bf16_8 a3 = *(const bf16_8*)(ap + 48 * DIN);
      acc0 = __builtin_amdgcn_mfma_f32_16x16x32_bf16(xv, a0, acc0, 0, 0, 0);
      acc1 = __builtin_amdgcn_mfma_f32_16x16x32_bf16(xv, a1, acc1, 0, 0, 0);
      acc2 = __builtin_amdgcn_mfma_f32_16x16x32_bf16(xv, a2, acc2, 0, 0, 0);
      acc3 = __builtin_amdgcn_mfma_f32_16x16x32_bf16(xv, a3, acc3, 0, 0, 0);
    }
    __syncthreads();   // drains stage (next buf ready) + LDS reads (WAR)
  }

  // cross-wave reduce over k-halves: partner waves w and w+2
#pragma unroll
  for (int i = 0; i < 4; ++i) {
    part[w][quad * 4 + i][     lr] = acc0[i];
    part[w][quad * 4 + i][16 + lr] = acc1[i];
    part[w][quad * 4 + i][32 + lr] = acc2[i];
    part[w][quad * 4 + i][48 + lr] = acc3[i];
  }
  __syncthreads();
  {
    int idx = t * 8;            // bf16 element index in [32][64]
    int r   = idx >> 6;         // 0..31
    int c   = idx & 63;
    int m2  = r >> 4, r16 = r & 15;
    f32x4 s0 = *(const f32x4*)&part[m2][r16][c]     + *(const f32x4*)&part[m2 + 2][r16][c];
    f32x4 s1 = *(const f32x4*)&part[m2][r16][c + 4] + *(const f32x4*)&part[m2 + 2][r16][c + 4];
    bf16_8 hv;
    hv[0]=(__bf16)s0[0]; hv[1]=(__bf16)s0[1]; hv[2]=(__bf16)s0[2]; hv[3]=(__bf16)s0[3];
    hv[4]=(__bf16)s1[0]; hv[5]=(__bf16)s1[1]; hv[6]=(__bf16)s1[2]; hv[7]=(__bf16)s1[3];
    *(bf16_8*)(h + (size_t)(mBase + r) * RANK + c) = hv;
  }
}

// ---------------- K2: out[M,4096] = h[M,64] @ Bbf[4096,64]^T ----------------
// 1024 blocks x 256 thr (4 waves). Per block: 16 rows x full N in 8 chunks of
// 512 cols. MFMA (operand-swapped) -> LDS bounce (XOR-swizzled) -> linear
// copy to global: each store instruction writes 1KB contiguous of one out row.
__global__ __launch_bounds__(256, 4) void gemm2_kernel(
    const __bf16* __restrict__ h, const __bf16* __restrict__ Bbf,
    float* __restrict__ out) {
  __shared__ alignas(16) float os[16][512];   // 32KB bounce

  const int t    = threadIdx.x;
  const int lane = t & 63;
  const int w    = t >> 6;
  const int lr   = lane & 15;
  const int quad = lane >> 4;
  const int mBase = blockIdx.x * 16;

  // h fragment (B-operand; col = m = lr): L2/L3-hot, read once
  const __bf16* hp = h + (size_t)(mBase + lr) * RANK + quad * 8;
  bf16_8 hf0 = *(const bf16_8*)(hp);
  bf16_8 hf1 = *(const bf16_8*)(hp + 32);

  for (int c = 0; c < 8; ++c) {
    const int nb = c * 512 + w * 128;      // wave's n-base this chunk
#pragma unroll
    for (int tt = 0; tt < 8; ++tt) {
      const __bf16* bp = Bbf + (size_t)(nb + tt * 16 + lr) * RANK + quad * 8;
      bf16_8 b0 = *(const bf16_8*)(bp);
      bf16_8 b1 = *(const bf16_8*)(bp + 32);
      f32x4 o = {0.f, 0.f, 0.f, 0.f};
      o = __builtin_amdgcn_mfma_f32_16x16x32_bf16(b0, hf0, o, 0, 0, 0);
      o = __builtin_amdgcn_mfma_f32_16x16x32_bf16(b1, hf1, o, 0, 0, 0);
      // D[row = n-in-tile = quad*4+i][col = m = lr]
      int colb = (w * 128 + tt * 16 + quad * 4) * 4;          // byte in 2KB row
      int addr = lr * 2048 + (colb ^ ((lr & 7) << 4));        // bank swizzle
      *(f32x4*)((char*)os + addr) = o;
    }
    __syncthreads();
    // linear copy os -> out: per instruction 1KB contiguous of one row
#pragma unroll
    for (int r = 0; r < 8; ++r) {
      int o4   = r * 4096 + t * 16;        // byte offset in 32KB tile
      int rr   = o4 >> 11;                 // row 0..15
      int colb = o4 & 2047;
      int a    = rr * 2048 + (colb ^ ((rr & 7) << 4));
      f32x4 v  = *(const f32x4*)((const char*)os + a);
      *(f32x4*)(out + (size_t)(mBase + rr) * DOUT + c * 512 + (colb >> 2)) = v;
    }
    __syncthreads();   // WAR: next chunk's MFMA writes vs this copy's reads
  }
}

extern "C" void kernel_launch(void* const* d_in, const int* in_sizes, int n_in,
                              void* d_out, int out_size, void* d_ws, size_t ws_size,
                              hipStream_t stream) {
  const float* x  = (const float*)d_in[0];
  const float* A  = (const float*)d_in[1];
  const float* Bm = (const float*)d_in[2];
  const float* sA = (const float*)d_in[3];
  const float* sB = (const float*)d_in[4];
  float* out = (float*)d_out;

  // workspace: Abf (512 KB) | Bbf (512 KB) | h (2 MB)
  __bf16* Abf = (__bf16*)d_ws;
  __bf16* Bbf = Abf + (size_t)RANK * DIN;
  __bf16* h   = Bbf + (size_t)DOUT * RANK;

  prep_kernel<<<256, 256, 0, stream>>>(A, Bm, sA, sB, Abf, Bbf);
  gemm1_kernel<<<M_TOTAL / 32, 256, 0, stream>>>(x, Abf, h);
  gemm2_kernel<<<M_TOTAL / 16, 256, 0, stream>>>(h, Bbf, out);
}